// Round 1
// baseline (3081.905 us; speedup 1.0000x reference)
//
#include <hip/hip_runtime.h>

// SectorGCN: 2-layer GCN (PyG GCNConv semantics) on MI355X.
// N=100000 nodes, E=3200000 edges, d_in=128, d_h=16, d_out=1.
//
// ws layout (floats):
//   deg  [N]      — degree accumulator (memset 0; self-loop +1 folded into rsqrt)
//   dinv [N]      — deg^{-1/2}
//   h    [N*16]   — x @ W1
//   agg1 [N*16]   — layer-1 aggregation accumulator (init = dinv^2 * h)
//   hs2  [N]      — per-node scalar after layer-2 linear
// total 35*N floats = 14 MB.

#define DH 16

__global__ void k_deg(const int* __restrict__ col, const float* __restrict__ ew,
                      float* __restrict__ deg, int E) {
    int e = blockIdx.x * blockDim.x + threadIdx.x;
    if (e < E) atomicAdd(&deg[col[e]], ew[e]);
}

// h = x @ W1 ; dinv = rsqrt(deg+1) ; agg1 = dinv^2 * h  (self-loop term)
// block = 256 threads = 16 nodes x 16 feats. N must be divisible by 16 (100000/16=6250).
__global__ __launch_bounds__(256) void k_h1(
    const float* __restrict__ x, const float* __restrict__ W1,
    const float* __restrict__ deg, float* __restrict__ dinv,
    float* __restrict__ h, float* __restrict__ agg1) {
    __shared__ float Ws[128 * DH];       // 8 KB
    __shared__ float xs[16 * 132];       // 16 rows, stride 132 (pad breaks 4-way conflict)
    const int t = threadIdx.x;
    const int node0 = blockIdx.x * 16;

    // load W1 (128x16 row-major), coalesced
    #pragma unroll
    for (int i = 0; i < 8; ++i) Ws[t + 256 * i] = W1[t + 256 * i];

    // load 16 x-rows (128 floats each) as float4, coalesced; LDS stride 132 (16B-aligned)
    const float4* xg = (const float4*)(x + (size_t)node0 * 128);
    #pragma unroll
    for (int it = 0; it < 2; ++it) {
        int idx = t + 256 * it;          // [0,512): float4 index
        int n = idx >> 5;                // row within tile
        int k4 = idx & 31;               // float4 within row
        float4 v = xg[n * 32 + k4];
        *(float4*)(&xs[n * 132 + k4 * 4]) = v;
    }
    __syncthreads();

    const int node = t >> 4;
    const int feat = t & 15;
    const float* xr = &xs[node * 132];
    float acc = 0.f;
    #pragma unroll 8
    for (int k = 0; k < 128; ++k) acc += xr[k] * Ws[k * DH + feat];

    const int v = node0 + node;
    const float di = rsqrtf(deg[v] + 1.0f);   // +1 = self-loop weight; deg>0 always
    if (feat == 0) dinv[v] = di;
    h[(size_t)v * DH + feat] = acc;
    agg1[(size_t)v * DH + feat] = di * di * acc;   // self-loop contribution
}

// layer-1 edge aggregation: agg1[c] += dinv[r]*w*dinv[c] * h[r]
__global__ void k_agg1(const int* __restrict__ row, const int* __restrict__ col,
                       const float* __restrict__ ew, const float* __restrict__ dinv,
                       const float* __restrict__ h, float* __restrict__ agg1, int E) {
    int e = blockIdx.x * blockDim.x + threadIdx.x;
    if (e >= E) return;
    const int r = row[e], c = col[e];
    const float norm = dinv[r] * ew[e] * dinv[c];
    const float4* hr = (const float4*)(h + (size_t)r * DH);
    float4 a = hr[0], b = hr[1], cc = hr[2], d = hr[3];
    float* out = agg1 + (size_t)c * DH;
    atomicAdd(out + 0,  norm * a.x);  atomicAdd(out + 1,  norm * a.y);
    atomicAdd(out + 2,  norm * a.z);  atomicAdd(out + 3,  norm * a.w);
    atomicAdd(out + 4,  norm * b.x);  atomicAdd(out + 5,  norm * b.y);
    atomicAdd(out + 6,  norm * b.z);  atomicAdd(out + 7,  norm * b.w);
    atomicAdd(out + 8,  norm * cc.x); atomicAdd(out + 9,  norm * cc.y);
    atomicAdd(out + 10, norm * cc.z); atomicAdd(out + 11, norm * cc.w);
    atomicAdd(out + 12, norm * d.x);  atomicAdd(out + 13, norm * d.y);
    atomicAdd(out + 14, norm * d.z);  atomicAdd(out + 15, norm * d.w);
}

// h1 = relu(agg1 + b1); hs2 = h1 . W2; out = b2 + dinv^2 * hs2  (layer-2 self-loop + bias)
__global__ void k_h2(const float* __restrict__ agg1, const float* __restrict__ b1,
                     const float* __restrict__ W2, const float* __restrict__ b2,
                     const float* __restrict__ dinv, float* __restrict__ hs2,
                     float* __restrict__ out, int N) {
    int v = blockIdx.x * blockDim.x + threadIdx.x;
    if (v >= N) return;
    const float4* ar = (const float4*)(agg1 + (size_t)v * DH);
    float acc = 0.f;
    #pragma unroll
    for (int q = 0; q < 4; ++q) {
        float4 a = ar[q];
        float4 bb = *(const float4*)(b1 + q * 4);
        float4 w = *(const float4*)(W2 + q * 4);
        acc += fmaxf(a.x + bb.x, 0.f) * w.x;
        acc += fmaxf(a.y + bb.y, 0.f) * w.y;
        acc += fmaxf(a.z + bb.z, 0.f) * w.z;
        acc += fmaxf(a.w + bb.w, 0.f) * w.w;
    }
    hs2[v] = acc;
    const float di = dinv[v];
    out[v] = b2[0] + di * di * acc;
}

// layer-2 edge aggregation: out[c] += dinv[r]*w*dinv[c] * hs2[r]
__global__ void k_agg2(const int* __restrict__ row, const int* __restrict__ col,
                       const float* __restrict__ ew, const float* __restrict__ dinv,
                       const float* __restrict__ hs2, float* __restrict__ out, int E) {
    int e = blockIdx.x * blockDim.x + threadIdx.x;
    if (e >= E) return;
    const int r = row[e], c = col[e];
    atomicAdd(&out[c], dinv[r] * ew[e] * dinv[c] * hs2[r]);
}

extern "C" void kernel_launch(void* const* d_in, const int* in_sizes, int n_in,
                              void* d_out, int out_size, void* d_ws, size_t ws_size,
                              hipStream_t stream) {
    const float* x  = (const float*)d_in[0];
    const int*   ei = (const int*)d_in[1];    // [2,E] (int inputs arrive as int32)
    const float* ew = (const float*)d_in[2];
    const float* W1 = (const float*)d_in[3];
    const float* b1 = (const float*)d_in[4];
    const float* W2 = (const float*)d_in[5];
    const float* b2 = (const float*)d_in[6];
    float* out = (float*)d_out;

    const int N = in_sizes[0] / 128;          // 100000
    const int E = in_sizes[2];                // 3200000
    const int* row = ei;
    const int* col = ei + E;

    float* ws   = (float*)d_ws;
    float* deg  = ws;                 // N
    float* dinv = ws + N;             // N
    float* h    = ws + 2 * (size_t)N; // N*16
    float* agg1 = h + 16 * (size_t)N; // N*16
    float* hs2  = agg1 + 16 * (size_t)N; // N

    hipMemsetAsync(deg, 0, (size_t)N * sizeof(float), stream);

    const int eb = (E + 255) / 256;
    k_deg<<<eb, 256, 0, stream>>>(col, ew, deg, E);
    k_h1<<<N / 16, 256, 0, stream>>>(x, W1, deg, dinv, h, agg1);
    k_agg1<<<eb, 256, 0, stream>>>(row, col, ew, dinv, h, agg1, E);
    k_h2<<<(N + 255) / 256, 256, 0, stream>>>(agg1, b1, W2, b2, dinv, hs2, out, N);
    k_agg2<<<eb, 256, 0, stream>>>(row, col, ew, dinv, hs2, out, E);
}

// Round 2
// 641.026 us; speedup vs baseline: 4.8078x; 4.8078x over previous
//
#include <hip/hip_runtime.h>

// SectorGCN R2: atomic-free aggregation via per-call CSR build.
// N=100000, E=3200000, d_in=128, d_h=16.
//
// Pipeline:
//   memset(cnt) ; hist(col) ; scan1/2/3 -> rowptr,cursor ; scatter -> edata(src,w)
//   deg_csr -> dinv ; GEMM h = x@W1 ; gather1 -> q = dinv * relu(agg+b1).W2
//   gather2 -> out = b2 + dinv*(sum w*q[src] + q[self])
//
// ws layout: cnt[N] rowptr[N+1] cursor[N] blocksum[512] (ints),
//            dinv[N] h[16N] q[N] (floats), edata[E] (uint2, 8B-aligned)

#define DH 16

__global__ void k_hist(const int* __restrict__ col, int* __restrict__ cnt, int E) {
    int e = blockIdx.x * blockDim.x + threadIdx.x;
    if (e < E) atomicAdd(&cnt[col[e]], 1);
}

// block-local inclusive scan of cnt -> rowptr (temp), block totals -> blocksum
__global__ __launch_bounds__(256) void k_scan1(const int* __restrict__ cnt,
                                               int* __restrict__ rowptr,
                                               int* __restrict__ blocksum, int N) {
    __shared__ int s[256];
    int i = blockIdx.x * 256 + threadIdx.x;
    int v = (i < N) ? cnt[i] : 0;
    s[threadIdx.x] = v;
    __syncthreads();
    for (int off = 1; off < 256; off <<= 1) {
        int t = (threadIdx.x >= off) ? s[threadIdx.x - off] : 0;
        __syncthreads();
        s[threadIdx.x] += t;
        __syncthreads();
    }
    if (i < N) rowptr[i] = s[threadIdx.x];
    if (threadIdx.x == 255) blocksum[blockIdx.x] = s[255];
}

// single-block exclusive scan of blocksum[nb], nb <= 512
__global__ __launch_bounds__(512) void k_scan2(int* __restrict__ blocksum, int nb) {
    __shared__ int s[512];
    int t = threadIdx.x;
    int v = (t < nb) ? blocksum[t] : 0;
    s[t] = v;
    __syncthreads();
    for (int off = 1; off < 512; off <<= 1) {
        int u = (t >= off) ? s[t - off] : 0;
        __syncthreads();
        s[t] += u;
        __syncthreads();
    }
    if (t < nb) blocksum[t] = s[t] - v;   // exclusive
}

// finalize exclusive rowptr, init cursor
__global__ void k_scan3(const int* __restrict__ cnt, int* __restrict__ rowptr,
                        const int* __restrict__ blocksum, int* __restrict__ cursor,
                        int N, int E) {
    int i = blockIdx.x * 256 + threadIdx.x;
    if (i < N) {
        int ex = blocksum[blockIdx.x] + rowptr[i] - cnt[i];
        rowptr[i] = ex;
        cursor[i] = ex;
    }
    if (i == 0) rowptr[N] = E;
}

__global__ void k_scatter(const int* __restrict__ row, const int* __restrict__ col,
                          const float* __restrict__ ew, int* __restrict__ cursor,
                          uint2* __restrict__ edata, int E) {
    int e = blockIdx.x * blockDim.x + threadIdx.x;
    if (e >= E) return;
    int slot = atomicAdd(&cursor[col[e]], 1);
    edata[slot] = make_uint2((unsigned)row[e], __float_as_uint(ew[e]));
}

// wave-per-node: deg = sum of in-edge weights; dinv = rsqrt(deg + 1 self-loop)
__global__ __launch_bounds__(256) void k_degcsr(const int* __restrict__ rowptr,
                                                const uint2* __restrict__ edata,
                                                float* __restrict__ dinv, int N) {
    int node = (blockIdx.x * 256 + threadIdx.x) >> 6;
    if (node >= N) return;
    int lane = threadIdx.x & 63;
    int base = rowptr[node], end = rowptr[node + 1];
    float s = 0.f;
    for (int i = base + lane; i < end; i += 64) s += __uint_as_float(edata[i].y);
    #pragma unroll
    for (int m = 1; m < 64; m <<= 1) s += __shfl_xor(s, m, 64);
    if (lane == 0) dinv[node] = rsqrtf(s + 1.0f);
}

// h = x @ W1. block = 256 = 16 nodes x 16 feats; N % 16 == 0.
__global__ __launch_bounds__(256) void k_h1(const float* __restrict__ x,
                                            const float* __restrict__ W1,
                                            float* __restrict__ h) {
    __shared__ float Ws[128 * DH];   // 8 KB
    __shared__ float xs[16 * 132];   // pad stride 132 breaks conflicts
    const int t = threadIdx.x;
    const int node0 = blockIdx.x * 16;

    #pragma unroll
    for (int i = 0; i < 8; ++i) Ws[t + 256 * i] = W1[t + 256 * i];

    const float4* xg = (const float4*)(x + (size_t)node0 * 128);
    #pragma unroll
    for (int it = 0; it < 2; ++it) {
        int idx = t + 256 * it;
        int n = idx >> 5, k4 = idx & 31;
        float4 v = xg[n * 32 + k4];
        *(float4*)(&xs[n * 132 + k4 * 4]) = v;
    }
    __syncthreads();

    const int node = t >> 4, feat = t & 15;
    const float* xr = &xs[node * 132];
    float acc = 0.f;
    #pragma unroll 8
    for (int k = 0; k < 128; ++k) acc += xr[k] * Ws[k * DH + feat];
    h[(size_t)(node0 + node) * DH + feat] = acc;
}

// wave-per-node fused layer-1 aggregate + bias + relu + dot(W2).
// lane = feat (0..15) x edge-subgroup g (0..3): 4 edges in flight,
// h-row reads are 64B coalesced per 16-lane group.
__global__ __launch_bounds__(256) void k_gather1(
    const int* __restrict__ rowptr, const uint2* __restrict__ edata,
    const float* __restrict__ dinv, const float* __restrict__ h,
    const float* __restrict__ b1, const float* __restrict__ W2,
    float* __restrict__ q, int N) {
    int node = (blockIdx.x * 256 + threadIdx.x) >> 6;
    if (node >= N) return;
    int lane = threadIdx.x & 63;
    int feat = lane & 15, g = lane >> 4;
    int base = rowptr[node], end = rowptr[node + 1];
    float acc = 0.f;
    for (int i = base + g; i < end; i += 4) {
        uint2 ed = edata[i];
        int r = ed.x;
        float w = __uint_as_float(ed.y);
        acc += dinv[r] * w * h[(size_t)r * DH + feat];
    }
    acc += __shfl_xor(acc, 16, 64);
    acc += __shfl_xor(acc, 32, 64);      // all lanes: full sum for their feat
    float dc = dinv[node];
    float ag = dc * acc + dc * dc * h[(size_t)node * DH + feat];  // + self-loop
    float t = fmaxf(ag + b1[feat], 0.f) * W2[feat];
    t += __shfl_xor(t, 1, 64);
    t += __shfl_xor(t, 2, 64);
    t += __shfl_xor(t, 4, 64);
    t += __shfl_xor(t, 8, 64);           // sum over 16 feats
    if (lane == 0) q[node] = dc * t;     // q = dinv * h2
}

// wave-per-node layer-2: out = b2 + dinv[c] * (sum_e w*q[src] + q[c])
__global__ __launch_bounds__(256) void k_gather2(
    const int* __restrict__ rowptr, const uint2* __restrict__ edata,
    const float* __restrict__ dinv, const float* __restrict__ q,
    const float* __restrict__ b2, float* __restrict__ out, int N) {
    int node = (blockIdx.x * 256 + threadIdx.x) >> 6;
    if (node >= N) return;
    int lane = threadIdx.x & 63;
    int base = rowptr[node], end = rowptr[node + 1];
    float acc = 0.f;
    for (int i = base + lane; i < end; i += 64) {
        uint2 ed = edata[i];
        acc += __uint_as_float(ed.y) * q[ed.x];
    }
    #pragma unroll
    for (int m = 1; m < 64; m <<= 1) acc += __shfl_xor(acc, m, 64);
    if (lane == 0) out[node] = b2[0] + dinv[node] * (acc + q[node]);
}

extern "C" void kernel_launch(void* const* d_in, const int* in_sizes, int n_in,
                              void* d_out, int out_size, void* d_ws, size_t ws_size,
                              hipStream_t stream) {
    const float* x  = (const float*)d_in[0];
    const int*   ei = (const int*)d_in[1];
    const float* ew = (const float*)d_in[2];
    const float* W1 = (const float*)d_in[3];
    const float* b1 = (const float*)d_in[4];
    const float* W2 = (const float*)d_in[5];
    const float* b2 = (const float*)d_in[6];
    float* out = (float*)d_out;

    const int N = in_sizes[0] / 128;   // 100000
    const int E = in_sizes[2];         // 3200000
    const int* row = ei;
    const int* col = ei + E;

    int* cnt      = (int*)d_ws;            // N
    int* rowptr   = cnt + N;               // N+1
    int* cursor   = rowptr + N + 1;        // N
    int* blocksum = cursor + N;            // 512
    float* dinv   = (float*)(blocksum + 512);  // N
    float* h      = dinv + N;              // 16N
    float* q      = h + (size_t)16 * N;    // N
    uintptr_t ep  = (uintptr_t)(q + N);
    ep = (ep + 7) & ~(uintptr_t)7;
    uint2* edata  = (uint2*)ep;            // E

    const int eb = (E + 255) / 256;        // 12500
    const int G1 = (N + 255) / 256;        // 391
    const int nodeb = (N * 64 + 255) / 256;  // 25000 (wave-per-node)

    hipMemsetAsync(cnt, 0, (size_t)N * sizeof(int), stream);
    k_hist<<<eb, 256, 0, stream>>>(col, cnt, E);
    k_scan1<<<G1, 256, 0, stream>>>(cnt, rowptr, blocksum, N);
    k_scan2<<<1, 512, 0, stream>>>(blocksum, G1);
    k_scan3<<<G1, 256, 0, stream>>>(cnt, rowptr, blocksum, cursor, N, E);
    k_scatter<<<eb, 256, 0, stream>>>(row, col, ew, cursor, edata, E);
    k_degcsr<<<nodeb, 256, 0, stream>>>(rowptr, edata, dinv, N);
    k_h1<<<N / 16, 256, 0, stream>>>(x, W1, h);
    k_gather1<<<nodeb, 256, 0, stream>>>(rowptr, edata, dinv, h, b1, W2, q, N);
    k_gather2<<<nodeb, 256, 0, stream>>>(rowptr, edata, dinv, q, b2, out, N);
}

// Round 3
// 589.885 us; speedup vs baseline: 5.2246x; 1.0867x over previous
//
#include <hip/hip_runtime.h>

// SectorGCN R3: bucket counting-sort (782 buckets x 128 nodes) + per-bucket
// LDS-atomic aggregation. No per-node CSR, no per-edge global atomics.
// N=100000, E=3200000, d_in=128, d_h=16.
//
// edata[i] = { row | (col&127)<<20 , float_bits(w) }, grouped by bucket=col>>7.
//
// ws: gCnt[NB] gBase[NB+1] gCursor[NB] (int) ; dinv[N] h[16N] q[N] (float) ;
//     edata[E] (uint2). ~33 MB.

#define DH 16
#define BSH 7                // 128 nodes / bucket
#define BNODES 128
#define NB_MAX 784           // ceil(100000/128)=782
#define CHUNK 4096           // edges per block in phase A

__global__ __launch_bounds__(256) void k_Ahist(const int* __restrict__ col,
                                               int* __restrict__ gCnt, int E, int NB) {
    __shared__ int lh[NB_MAX];
    const int tid = threadIdx.x;
    for (int i = tid; i < NB; i += 256) lh[i] = 0;
    __syncthreads();
    const int base = blockIdx.x * CHUNK;
    #pragma unroll
    for (int k = 0; k < 16; ++k) {
        int e = base + tid + 256 * k;
        if (e < E) atomicAdd(&lh[col[e] >> BSH], 1);
    }
    __syncthreads();
    for (int i = tid; i < NB; i += 256) {
        int v = lh[i];
        if (v) atomicAdd(&gCnt[i], v);
    }
}

__global__ __launch_bounds__(1024) void k_Ascan(const int* __restrict__ gCnt,
                                                int* __restrict__ gBase,
                                                int* __restrict__ gCursor,
                                                int NB, int E) {
    __shared__ int s[1024];
    const int t = threadIdx.x;
    int v = (t < NB) ? gCnt[t] : 0;
    s[t] = v;
    __syncthreads();
    for (int off = 1; off < 1024; off <<= 1) {
        int u = (t >= off) ? s[t - off] : 0;
        __syncthreads();
        s[t] += u;
        __syncthreads();
    }
    if (t < NB) {
        int ex = s[t] - v;
        gBase[t] = ex;
        gCursor[t] = ex;
    }
    if (t == 0) gBase[NB] = E;
}

__global__ __launch_bounds__(256) void k_Ascatter(const int* __restrict__ row,
                                                  const int* __restrict__ col,
                                                  const float* __restrict__ ew,
                                                  int* __restrict__ gCursor,
                                                  uint2* __restrict__ edata,
                                                  int E, int NB) {
    __shared__ int lh[NB_MAX], lbase[NB_MAX], lcur[NB_MAX];
    const int tid = threadIdx.x;
    for (int i = tid; i < NB; i += 256) lh[i] = 0;
    __syncthreads();
    const int base = blockIdx.x * CHUNK;
    int r_[16], c_[16];
    float w_[16];
    #pragma unroll
    for (int k = 0; k < 16; ++k) {
        int e = base + tid + 256 * k;
        bool ok = e < E;
        c_[k] = ok ? col[e] : -1;
        r_[k] = ok ? row[e] : 0;
        w_[k] = ok ? ew[e] : 0.f;
        if (ok) atomicAdd(&lh[c_[k] >> BSH], 1);
    }
    __syncthreads();
    for (int b = tid; b < NB; b += 256) {
        int v = lh[b];
        if (v) {
            lbase[b] = atomicAdd(&gCursor[b], v);
            lcur[b] = 0;
        }
    }
    __syncthreads();
    #pragma unroll
    for (int k = 0; k < 16; ++k) {
        if (c_[k] >= 0) {
            int b = c_[k] >> BSH;
            int rem = c_[k] & (BNODES - 1);
            int off = atomicAdd(&lcur[b], 1);
            edata[lbase[b] + off] =
                make_uint2((unsigned)r_[k] | ((unsigned)rem << 20), __float_as_uint(w_[k]));
        }
    }
}

// per-bucket: deg sum in LDS, dinv = rsqrt(deg + 1)
__global__ __launch_bounds__(256) void k_deg(const int* __restrict__ gBase,
                                             const uint2* __restrict__ edata,
                                             float* __restrict__ dinv, int N) {
    __shared__ float dg[BNODES];
    const int tid = threadIdx.x;
    if (tid < BNODES) dg[tid] = 0.f;
    __syncthreads();
    const int s = gBase[blockIdx.x], e = gBase[blockIdx.x + 1];
    for (int i = s + tid; i < e; i += 256) {
        uint2 ed = edata[i];
        atomicAdd(&dg[ed.x >> 20], __uint_as_float(ed.y));
    }
    __syncthreads();
    int node = (blockIdx.x << BSH) + tid;
    if (tid < BNODES && node < N) dinv[node] = rsqrtf(dg[tid] + 1.0f);
}

// h = x @ W1. block = 256 = 16 nodes x 16 feats.
__global__ __launch_bounds__(256) void k_h1(const float* __restrict__ x,
                                            const float* __restrict__ W1,
                                            float* __restrict__ h) {
    __shared__ float Ws[128 * DH];
    __shared__ float xs[16 * 132];
    const int t = threadIdx.x;
    const int node0 = blockIdx.x * 16;
    #pragma unroll
    for (int i = 0; i < 8; ++i) Ws[t + 256 * i] = W1[t + 256 * i];
    const float4* xg = (const float4*)(x + (size_t)node0 * 128);
    #pragma unroll
    for (int it = 0; it < 2; ++it) {
        int idx = t + 256 * it;
        int n = idx >> 5, k4 = idx & 31;
        float4 v = xg[n * 32 + k4];
        *(float4*)(&xs[n * 132 + k4 * 4]) = v;
    }
    __syncthreads();
    const int node = t >> 4, feat = t & 15;
    const float* xr = &xs[node * 132];
    float acc = 0.f;
    #pragma unroll 8
    for (int k = 0; k < 128; ++k) acc += xr[k] * Ws[k * DH + feat];
    h[(size_t)(node0 + node) * DH + feat] = acc;
}

// per-bucket fused layer-1: acc[f][rem] += w*dinv[r]*h[r][f] (LDS atomics),
// then q[node] = dinv * sum_f relu(dinv*acc + dinv^2*h_self + b1)*W2
__global__ __launch_bounds__(256) void k_gather1(
    const int* __restrict__ gBase, const uint2* __restrict__ edata,
    const float* __restrict__ dinv, const float* __restrict__ h,
    const float* __restrict__ b1, const float* __restrict__ W2,
    float* __restrict__ q, int N) {
    __shared__ float acc[DH][BNODES + 1];
    __shared__ float b1s[DH], W2s[DH];
    const int tid = threadIdx.x;
    if (tid < DH) { b1s[tid] = b1[tid]; W2s[tid] = W2[tid]; }
    for (int i = tid; i < DH * (BNODES + 1); i += 256) ((float*)acc)[i] = 0.f;
    __syncthreads();
    const int s = gBase[blockIdx.x], e = gBase[blockIdx.x + 1];
    const int g = tid >> 4, f = tid & 15;   // 16 groups x 16 feats
    for (int i = s + g; i < e; i += 16) {
        uint2 ed = edata[i];
        int r = ed.x & 0xFFFFF;
        int rem = ed.x >> 20;
        float w = __uint_as_float(ed.y);
        atomicAdd(&acc[f][rem], w * dinv[r] * h[r * DH + f]);
    }
    __syncthreads();
    int node = (blockIdx.x << BSH) + tid;
    if (tid < BNODES && node < N) {
        float dc = dinv[node];
        float t = 0.f;
        #pragma unroll
        for (int ff = 0; ff < DH; ++ff) {
            float ag = dc * acc[ff][tid] + dc * dc * h[node * DH + ff];
            t += fmaxf(ag + b1s[ff], 0.f) * W2s[ff];
        }
        q[node] = dc * t;
    }
}

// per-bucket layer-2: a2[rem] += w*q[r]; out = b2 + dinv*(a2 + q_self)
__global__ __launch_bounds__(256) void k_gather2(
    const int* __restrict__ gBase, const uint2* __restrict__ edata,
    const float* __restrict__ dinv, const float* __restrict__ q,
    const float* __restrict__ b2, float* __restrict__ out, int N) {
    __shared__ float a2[BNODES];
    const int tid = threadIdx.x;
    if (tid < BNODES) a2[tid] = 0.f;
    __syncthreads();
    const int s = gBase[blockIdx.x], e = gBase[blockIdx.x + 1];
    for (int i = s + tid; i < e; i += 256) {
        uint2 ed = edata[i];
        int r = ed.x & 0xFFFFF;
        atomicAdd(&a2[ed.x >> 20], __uint_as_float(ed.y) * q[r]);
    }
    __syncthreads();
    int node = (blockIdx.x << BSH) + tid;
    if (tid < BNODES && node < N)
        out[node] = b2[0] + dinv[node] * (a2[tid] + q[node]);
}

extern "C" void kernel_launch(void* const* d_in, const int* in_sizes, int n_in,
                              void* d_out, int out_size, void* d_ws, size_t ws_size,
                              hipStream_t stream) {
    const float* x  = (const float*)d_in[0];
    const int*   ei = (const int*)d_in[1];
    const float* ew = (const float*)d_in[2];
    const float* W1 = (const float*)d_in[3];
    const float* b1 = (const float*)d_in[4];
    const float* W2 = (const float*)d_in[5];
    const float* b2 = (const float*)d_in[6];
    float* out = (float*)d_out;

    const int N = in_sizes[0] / 128;       // 100000
    const int E = in_sizes[2];             // 3200000
    const int* row = ei;
    const int* col = ei + E;
    const int NB = (N + BNODES - 1) >> BSH;  // 782

    int* gCnt    = (int*)d_ws;             // NB
    int* gBase   = gCnt + NB;              // NB+1
    int* gCursor = gBase + NB + 1;         // NB
    float* dinv  = (float*)(gCursor + NB); // N
    float* h     = dinv + N;               // 16N
    float* q     = h + (size_t)16 * N;     // N
    uintptr_t ep = (uintptr_t)(q + N);
    ep = (ep + 7) & ~(uintptr_t)7;
    uint2* edata = (uint2*)ep;             // E

    const int ablocks = (E + CHUNK - 1) / CHUNK;   // 782

    hipMemsetAsync(gCnt, 0, (size_t)NB * sizeof(int), stream);
    k_Ahist<<<ablocks, 256, 0, stream>>>(col, gCnt, E, NB);
    k_Ascan<<<1, 1024, 0, stream>>>(gCnt, gBase, gCursor, NB, E);
    k_Ascatter<<<ablocks, 256, 0, stream>>>(row, col, ew, gCursor, edata, E, NB);
    k_deg<<<NB, 256, 0, stream>>>(gBase, edata, dinv, N);
    k_h1<<<N / 16, 256, 0, stream>>>(x, W1, h);
    k_gather1<<<NB, 256, 0, stream>>>(gBase, edata, dinv, h, b1, W2, q, N);
    k_gather2<<<NB, 256, 0, stream>>>(gBase, edata, dinv, q, b2, out, N);
}

// Round 4
// 533.134 us; speedup vs baseline: 5.7807x; 1.1064x over previous
//
#include <hip/hip_runtime.h>

// SectorGCN R4: bucket counting-sort (782 x 128 nodes) + SLICED per-bucket
// gather (4 slice-blocks per bucket, LDS accumulate -> partial strips ->
// streaming reduce). No per-edge global atomics anywhere.
// N=100000, E=3200000, d_in=128, d_h=16.

#define DH 16
#define BSH 7
#define BNODES 128
#define NB_MAX 784
#define CHUNK 4096
#define NSLICE 4

__global__ __launch_bounds__(256) void k_Ahist(const int* __restrict__ col,
                                               int* __restrict__ gCnt, int E, int NB) {
    __shared__ int lh[NB_MAX];
    const int tid = threadIdx.x;
    for (int i = tid; i < NB; i += 256) lh[i] = 0;
    __syncthreads();
    const int base = blockIdx.x * CHUNK;
    #pragma unroll
    for (int k = 0; k < 16; ++k) {
        int e = base + tid + 256 * k;
        if (e < E) atomicAdd(&lh[col[e] >> BSH], 1);
    }
    __syncthreads();
    for (int i = tid; i < NB; i += 256) {
        int v = lh[i];
        if (v) atomicAdd(&gCnt[i], v);
    }
}

__global__ __launch_bounds__(1024) void k_Ascan(const int* __restrict__ gCnt,
                                                int* __restrict__ gBase,
                                                int* __restrict__ gCursor,
                                                int NB, int E) {
    __shared__ int s[1024];
    const int t = threadIdx.x;
    int v = (t < NB) ? gCnt[t] : 0;
    s[t] = v;
    __syncthreads();
    for (int off = 1; off < 1024; off <<= 1) {
        int u = (t >= off) ? s[t - off] : 0;
        __syncthreads();
        s[t] += u;
        __syncthreads();
    }
    if (t < NB) {
        int ex = s[t] - v;
        gBase[t] = ex;
        gCursor[t] = ex;
    }
    if (t == 0) gBase[NB] = E;
}

__global__ __launch_bounds__(256) void k_Ascatter(const int* __restrict__ row,
                                                  const int* __restrict__ col,
                                                  const float* __restrict__ ew,
                                                  int* __restrict__ gCursor,
                                                  uint2* __restrict__ edata,
                                                  int E, int NB) {
    __shared__ int lh[NB_MAX], lbase[NB_MAX], lcur[NB_MAX];
    const int tid = threadIdx.x;
    for (int i = tid; i < NB; i += 256) lh[i] = 0;
    __syncthreads();
    const int base = blockIdx.x * CHUNK;
    int r_[16], c_[16];
    float w_[16];
    #pragma unroll
    for (int k = 0; k < 16; ++k) {
        int e = base + tid + 256 * k;
        bool ok = e < E;
        c_[k] = ok ? col[e] : -1;
        r_[k] = ok ? row[e] : 0;
        w_[k] = ok ? ew[e] : 0.f;
        if (ok) atomicAdd(&lh[c_[k] >> BSH], 1);
    }
    __syncthreads();
    for (int b = tid; b < NB; b += 256) {
        int v = lh[b];
        if (v) {
            lbase[b] = atomicAdd(&gCursor[b], v);
            lcur[b] = 0;
        }
    }
    __syncthreads();
    #pragma unroll
    for (int k = 0; k < 16; ++k) {
        if (c_[k] >= 0) {
            int b = c_[k] >> BSH;
            int rem = c_[k] & (BNODES - 1);
            int off = atomicAdd(&lcur[b], 1);
            edata[lbase[b] + off] =
                make_uint2((unsigned)r_[k] | ((unsigned)rem << 20), __float_as_uint(w_[k]));
        }
    }
}

__global__ __launch_bounds__(256) void k_deg(const int* __restrict__ gBase,
                                             const uint2* __restrict__ edata,
                                             float* __restrict__ dinv, int N) {
    __shared__ float dg[BNODES];
    const int tid = threadIdx.x;
    if (tid < BNODES) dg[tid] = 0.f;
    __syncthreads();
    const int s = gBase[blockIdx.x], e = gBase[blockIdx.x + 1];
    for (int i = s + tid; i < e; i += 256) {
        uint2 ed = edata[i];
        atomicAdd(&dg[ed.x >> 20], __uint_as_float(ed.y));
    }
    __syncthreads();
    int node = (blockIdx.x << BSH) + tid;
    if (tid < BNODES && node < N) dinv[node] = rsqrtf(dg[tid] + 1.0f);
}

// h = x @ W1
__global__ __launch_bounds__(256) void k_h1(const float* __restrict__ x,
                                            const float* __restrict__ W1,
                                            float* __restrict__ h) {
    __shared__ float Ws[128 * DH];
    __shared__ float xs[16 * 132];
    const int t = threadIdx.x;
    const int node0 = blockIdx.x * 16;
    #pragma unroll
    for (int i = 0; i < 8; ++i) Ws[t + 256 * i] = W1[t + 256 * i];
    const float4* xg = (const float4*)(x + (size_t)node0 * 128);
    #pragma unroll
    for (int it = 0; it < 2; ++it) {
        int idx = t + 256 * it;
        int n = idx >> 5, k4 = idx & 31;
        float4 v = xg[n * 32 + k4];
        *(float4*)(&xs[n * 132 + k4 * 4]) = v;
    }
    __syncthreads();
    const int node = t >> 4, feat = t & 15;
    const float* xr = &xs[node * 132];
    float acc = 0.f;
    #pragma unroll 8
    for (int k = 0; k < 128; ++k) acc += xr[k] * Ws[k * DH + feat];
    h[(size_t)(node0 + node) * DH + feat] = acc;
}

// sliced layer-1 gather: block (bucket b, slice sl) accumulates
// acc[f][rem] += w*dinv[r]*h[r][f] over edges i in [s,e), i ≡ sl*16+g (mod 64),
// unrolled x2; writes 16x128 partial strip.
__global__ __launch_bounds__(256) void k_gather1(
    const int* __restrict__ gBase, const uint2* __restrict__ edata,
    const float* __restrict__ dinv, const float* __restrict__ h,
    float* __restrict__ partial) {
    __shared__ float acc[DH][BNODES + 1];
    const int tid = threadIdx.x;
    for (int i = tid; i < DH * (BNODES + 1); i += 256) ((float*)acc)[i] = 0.f;
    __syncthreads();
    const int b = blockIdx.x, sl = blockIdx.y;
    const int s = gBase[b], e = gBase[b + 1];
    const int g = tid >> 4, f = tid & 15;
    for (int i = s + sl * 16 + g; i < e; i += 128) {
        uint2 ed0 = edata[i];
        int i1 = i + 64;
        uint2 ed1 = (i1 < e) ? edata[i1] : make_uint2(0u, 0u);  // w=0 -> adds 0 to acc[f][0]
        int r0 = ed0.x & 0xFFFFF;
        int r1 = ed1.x & 0xFFFFF;
        float w0 = __uint_as_float(ed0.y), w1 = __uint_as_float(ed1.y);
        float v0 = w0 * dinv[r0] * h[r0 * DH + f];
        float v1 = w1 * dinv[r1] * h[r1 * DH + f];
        atomicAdd(&acc[f][ed0.x >> 20], v0);
        atomicAdd(&acc[f][ed1.x >> 20], v1);
    }
    __syncthreads();
    // store 16x128 strip, coalesced
    float* ps = partial + ((size_t)b * NSLICE + sl) * (DH * BNODES);
    #pragma unroll
    for (int i = tid; i < DH * BNODES; i += 256)
        ps[i] = acc[i >> BSH][i & (BNODES - 1)];
}

// reduce slices + self-loop + bias + relu + dot(W2) -> q
__global__ __launch_bounds__(256) void k_fin1(
    const float* __restrict__ partial, const float* __restrict__ dinv,
    const float* __restrict__ h, const float* __restrict__ b1,
    const float* __restrict__ W2, float* __restrict__ q, int N) {
    __shared__ float acc[DH][BNODES + 1];
    __shared__ float b1s[DH], W2s[DH];
    const int tid = threadIdx.x;
    if (tid < DH) { b1s[tid] = b1[tid]; W2s[tid] = W2[tid]; }
    const int b = blockIdx.x;
    const float* ps = partial + (size_t)b * NSLICE * (DH * BNODES);
    for (int i = tid; i < DH * BNODES; i += 256) {
        float s = 0.f;
        #pragma unroll
        for (int sl = 0; sl < NSLICE; ++sl) s += ps[sl * (DH * BNODES) + i];
        acc[i >> BSH][i & (BNODES - 1)] = s;
    }
    __syncthreads();
    int node = (b << BSH) + tid;
    if (tid < BNODES && node < N) {
        float dc = dinv[node];
        float t = 0.f;
        #pragma unroll
        for (int ff = 0; ff < DH; ++ff) {
            float ag = dc * acc[ff][tid] + dc * dc * h[node * DH + ff];
            t += fmaxf(ag + b1s[ff], 0.f) * W2s[ff];
        }
        q[node] = dc * t;
    }
}

// layer-2: a2[rem] += w*q[r]; out = b2 + dinv*(a2 + q_self)
__global__ __launch_bounds__(256) void k_gather2(
    const int* __restrict__ gBase, const uint2* __restrict__ edata,
    const float* __restrict__ dinv, const float* __restrict__ q,
    const float* __restrict__ b2, float* __restrict__ out, int N) {
    __shared__ float a2[BNODES];
    const int tid = threadIdx.x;
    if (tid < BNODES) a2[tid] = 0.f;
    __syncthreads();
    const int s = gBase[blockIdx.x], e = gBase[blockIdx.x + 1];
    for (int i = s + tid; i < e; i += 512) {
        uint2 ed0 = edata[i];
        int i1 = i + 256;
        uint2 ed1 = (i1 < e) ? edata[i1] : make_uint2(0u, 0u);
        float v0 = __uint_as_float(ed0.y) * q[ed0.x & 0xFFFFF];
        float v1 = __uint_as_float(ed1.y) * q[ed1.x & 0xFFFFF];
        atomicAdd(&a2[ed0.x >> 20], v0);
        atomicAdd(&a2[ed1.x >> 20], v1);
    }
    __syncthreads();
    int node = (blockIdx.x << BSH) + tid;
    if (tid < BNODES && node < N)
        out[node] = b2[0] + dinv[node] * (a2[tid] + q[node]);
}

extern "C" void kernel_launch(void* const* d_in, const int* in_sizes, int n_in,
                              void* d_out, int out_size, void* d_ws, size_t ws_size,
                              hipStream_t stream) {
    const float* x  = (const float*)d_in[0];
    const int*   ei = (const int*)d_in[1];
    const float* ew = (const float*)d_in[2];
    const float* W1 = (const float*)d_in[3];
    const float* b1 = (const float*)d_in[4];
    const float* W2 = (const float*)d_in[5];
    const float* b2 = (const float*)d_in[6];
    float* out = (float*)d_out;

    const int N = in_sizes[0] / 128;       // 100000
    const int E = in_sizes[2];             // 3200000
    const int* row = ei;
    const int* col = ei + E;
    const int NB = (N + BNODES - 1) >> BSH;  // 782

    int* gCnt    = (int*)d_ws;             // NB
    int* gBase   = gCnt + NB;              // NB+1
    int* gCursor = gBase + NB + 1;         // NB
    float* dinv  = (float*)(gCursor + NB); // N
    float* h     = dinv + N;               // 16N
    float* q     = h + (size_t)16 * N;     // N
    float* partial = q + N;                // NB*NSLICE*2048 = 25.6 MB
    uintptr_t ep = (uintptr_t)(partial + (size_t)NB * NSLICE * (DH * BNODES));
    ep = (ep + 7) & ~(uintptr_t)7;
    uint2* edata = (uint2*)ep;             // E

    const int ablocks = (E + CHUNK - 1) / CHUNK;   // 782

    hipMemsetAsync(gCnt, 0, (size_t)NB * sizeof(int), stream);
    k_Ahist<<<ablocks, 256, 0, stream>>>(col, gCnt, E, NB);
    k_Ascan<<<1, 1024, 0, stream>>>(gCnt, gBase, gCursor, NB, E);
    k_Ascatter<<<ablocks, 256, 0, stream>>>(row, col, ew, gCursor, edata, E, NB);
    k_deg<<<NB, 256, 0, stream>>>(gBase, edata, dinv, N);
    k_h1<<<N / 16, 256, 0, stream>>>(x, W1, h);
    k_gather1<<<dim3(NB, NSLICE), 256, 0, stream>>>(gBase, edata, dinv, h, partial);
    k_fin1<<<NB, 256, 0, stream>>>(partial, dinv, h, b1, W2, q, N);
    k_gather2<<<NB, 256, 0, stream>>>(gBase, edata, dinv, q, b2, out, N);
}